// Round 16
// baseline (196.497 us; speedup 1.0000x reference)
//
#include <hip/hip_runtime.h>
#include <stdint.h>

// ---------------------------------------------------------------------------
// Fused MHA block: qkv proj -> flash attention -> out proj.
// Inputs fp32, output fp32; bf16 MFMA compute, fp32 accum.
// B=4 N=2048 C=512 H=8 D=64 fixed.
// R16: attn restored to R14 (best); GEMMs rebuilt LDS-free/barrier-free:
// XCD remap keeps A-slice+B L2-resident, waves MFMA straight from register
// fragments loaded from L2 (2-deep pipeline). No syncthreads in GEMMs.
// ---------------------------------------------------------------------------

typedef short bf16x8 __attribute__((ext_vector_type(8)));   // 8 bf16 = 4 VGPRs
typedef float f32x2  __attribute__((ext_vector_type(2)));
typedef float f32x4  __attribute__((ext_vector_type(4)));
typedef float f32x16 __attribute__((ext_vector_type(16)));
typedef unsigned int u32x4 __attribute__((ext_vector_type(4)));

__device__ __forceinline__ unsigned short f2bf(float f) {
    unsigned int u = __builtin_bit_cast(unsigned int, f);
    u += 0x7fffu + ((u >> 16) & 1u);
    return (unsigned short)(u >> 16);
}
__device__ __forceinline__ unsigned int pk2(float a, float b) {
    return (unsigned int)f2bf(a) | ((unsigned int)f2bf(b) << 16);
}
__device__ __forceinline__ float fexp2(float x) {
    return __builtin_amdgcn_exp2f(x);    // bare v_exp_f32
}
__device__ __forceinline__ bf16x8 ld8_f32(const float* __restrict__ p) {
    float4 f0 = *(const float4*)p;
    float4 f1 = *(const float4*)(p + 4);
    u32x4 u = {pk2(f0.x, f0.y), pk2(f0.z, f0.w), pk2(f1.x, f1.y), pk2(f1.z, f1.w)};
    return __builtin_bit_cast(bf16x8, u);
}
__device__ __forceinline__ void async16(const void* g, void* l) {
    __builtin_amdgcn_global_load_lds(
        (const __attribute__((address_space(1))) unsigned int*)g,
        (__attribute__((address_space(3))) unsigned int*)l,
        16, 0, 0);
}

#define MFMA16(a, b, c) __builtin_amdgcn_mfma_f32_16x16x32_bf16((a), (b), (c), 0, 0, 0)
#define MFMA32(a, b, c) __builtin_amdgcn_mfma_f32_32x32x16_bf16((a), (b), (c), 0, 0, 0)

// ---------------------------------------------------------------------------
// fp32 -> bf16 bulk converts
// ---------------------------------------------------------------------------
__global__ void cvt_bf16(const float* __restrict__ x,
                         const float* __restrict__ w,
                         unsigned short* __restrict__ xb,
                         unsigned short* __restrict__ wb)
{
    const int G = 524288 + 98304;
    for (int idx = blockIdx.x * 256 + threadIdx.x; idx < G; idx += gridDim.x * 256) {
        if (idx < 524288)
            *(bf16x8*)(xb + (size_t)idx * 8) = ld8_f32(x + (size_t)idx * 8);
        else {
            int j = idx - 524288;
            *(bf16x8*)(wb + (size_t)j * 8) = ld8_f32(w + (size_t)j * 8);
        }
    }
}
__global__ void cvt_w2(const float* __restrict__ w, unsigned short* __restrict__ wb)
{
    int idx = blockIdx.x * 256 + threadIdx.x;   // exactly 32768
    *(bf16x8*)(wb + (size_t)idx * 8) = ld8_f32(w + (size_t)idx * 8);
}

// ---------------------------------------------------------------------------
// QKV GEMM, LDS-free: each wave computes 64x64 via register fragments read
// straight from L2 (XCD remap keeps A-slice 1MB + B 1.5MB resident).
// 2-deep register pipeline over k; zero barriers.
// ---------------------------------------------------------------------------
__global__ __launch_bounds__(256, 3)
void gemm_qkv(const unsigned short* __restrict__ A,
              const unsigned short* __restrict__ B,
              const float* __restrict__ bias,
              unsigned short* __restrict__ out0,
              unsigned short* __restrict__ out1,
              unsigned short* __restrict__ out2,
              int K)
{
    const int tid  = threadIdx.x;
    const int wave = tid >> 6, lane = tid & 63;
    const int l = lane & 15, q16 = lane >> 4;
    const int wm = wave >> 1, wn = wave & 1;
    const int bid = blockIdx.x;                  // 0..767
    const int slot = bid >> 3;                   // 0..95
    const int m0 = ((bid & 7) * 8 + slot / 12) * 128;
    const int n0 = (slot % 12) * 128;

    const unsigned short* Ap = A + (size_t)(m0 + wm * 64 + l) * K + q16 * 8;
    const unsigned short* Bp = B + (size_t)(n0 + wn * 64 + l) * K + q16 * 8;
    const size_t rstep = (size_t)16 * K;         // 16-row stride

    f32x4 acc[4][4];
#pragma unroll
    for (int i = 0; i < 4; ++i)
#pragma unroll
        for (int j = 0; j < 4; ++j)
            acc[i][j] = (f32x4){0.f, 0.f, 0.f, 0.f};

    bf16x8 a0[4], b0[4], a1[4], b1[4];
#pragma unroll
    for (int i = 0; i < 4; ++i) {
        a0[i] = *(const bf16x8*)(Ap + i * rstep);
        b0[i] = *(const bf16x8*)(Bp + i * rstep);
    }
    for (int k0 = 0; k0 < K; k0 += 64) {
        // prefetch k0+32
#pragma unroll
        for (int i = 0; i < 4; ++i) {
            a1[i] = *(const bf16x8*)(Ap + i * rstep + k0 + 32);
            b1[i] = *(const bf16x8*)(Bp + i * rstep + k0 + 32);
        }
#pragma unroll
        for (int i = 0; i < 4; ++i)
#pragma unroll
            for (int j = 0; j < 4; ++j)
                acc[i][j] = MFMA16(a0[i], b0[j], acc[i][j]);
        if (k0 + 64 < K) {
#pragma unroll
            for (int i = 0; i < 4; ++i) {
                a0[i] = *(const bf16x8*)(Ap + i * rstep + k0 + 64);
                b0[i] = *(const bf16x8*)(Bp + i * rstep + k0 + 64);
            }
        }
#pragma unroll
        for (int i = 0; i < 4; ++i)
#pragma unroll
            for (int j = 0; j < 4; ++j)
                acc[i][j] = MFMA16(a1[i], b1[j], acc[i][j]);
    }

    const float lscale = 0.18033688f;  // D^-0.5 * log2(e), folded into q
#pragma unroll
    for (int i = 0; i < 4; ++i) {
#pragma unroll
        for (int j = 0; j < 4; ++j) {
            int col = n0 + wn * 64 + j * 16 + l;
            float bv = bias[col];
#pragma unroll
            for (int r = 0; r < 4; ++r) {
                int row = m0 + wm * 64 + i * 16 + q16 * 4 + r;
                float val = acc[i][j][r] + bv;
                int which = col >> 9;            // 0:q 1:k 2:v
                int h = (col >> 6) & 7, d = col & 63;
                int b = row >> 11, n = row & 2047;
                if (which == 0)
                    out0[(size_t)(((b * 8 + h) * 2048) + n) * 64 + d] = f2bf(val * lscale);
                else if (which == 1)
                    out1[(size_t)(((b * 8 + h) * 2048) + n) * 64 + d] = f2bf(val);
                else {
                    // V^T with pi(n): swap bits 2<->3 of n (within 32-blocks)
                    int np = (n & ~12) | ((n & 8) >> 1) | ((n & 4) << 1);
                    out2[(size_t)(((b * 8 + h) * 64) + d) * 2048 + np] = f2bf(val);
                }
            }
        }
    }
}

// ---------------------------------------------------------------------------
// Output GEMM, LDS-free (wave = 32x64 tile), zero barriers. fp32 out + bias.
// ---------------------------------------------------------------------------
__global__ __launch_bounds__(256, 4)
void gemm_out(const unsigned short* __restrict__ A,
              const unsigned short* __restrict__ B,
              const float* __restrict__ bias,
              float* __restrict__ outf,
              int K, int N)
{
    const int tid  = threadIdx.x;
    const int wave = tid >> 6, lane = tid & 63;
    const int l = lane & 15, q16 = lane >> 4;
    const int wm = wave >> 1, wn = wave & 1;
    const int bid = blockIdx.x;                  // 0..511
    const int slot = bid >> 3;                   // 0..63
    const int m0 = ((bid & 7) * 16 + (slot >> 2)) * 64;
    const int n0 = (slot & 3) * 128;

    const unsigned short* Ap = A + (size_t)(m0 + wm * 32 + l) * K + q16 * 8;
    const unsigned short* Bp = B + (size_t)(n0 + wn * 64 + l) * K + q16 * 8;
    const size_t rstep = (size_t)16 * K;

    f32x4 acc[2][4];
#pragma unroll
    for (int i = 0; i < 2; ++i)
#pragma unroll
        for (int j = 0; j < 4; ++j)
            acc[i][j] = (f32x4){0.f, 0.f, 0.f, 0.f};

    bf16x8 a0[2], b0[4], a1[2], b1[4];
#pragma unroll
    for (int i = 0; i < 2; ++i) a0[i] = *(const bf16x8*)(Ap + i * rstep);
#pragma unroll
    for (int j = 0; j < 4; ++j) b0[j] = *(const bf16x8*)(Bp + j * rstep);

    for (int k0 = 0; k0 < K; k0 += 64) {
#pragma unroll
        for (int i = 0; i < 2; ++i) a1[i] = *(const bf16x8*)(Ap + i * rstep + k0 + 32);
#pragma unroll
        for (int j = 0; j < 4; ++j) b1[j] = *(const bf16x8*)(Bp + j * rstep + k0 + 32);
#pragma unroll
        for (int i = 0; i < 2; ++i)
#pragma unroll
            for (int j = 0; j < 4; ++j)
                acc[i][j] = MFMA16(a0[i], b0[j], acc[i][j]);
        if (k0 + 64 < K) {
#pragma unroll
            for (int i = 0; i < 2; ++i) a0[i] = *(const bf16x8*)(Ap + i * rstep + k0 + 64);
#pragma unroll
            for (int j = 0; j < 4; ++j) b0[j] = *(const bf16x8*)(Bp + j * rstep + k0 + 64);
        }
#pragma unroll
        for (int i = 0; i < 2; ++i)
#pragma unroll
            for (int j = 0; j < 4; ++j)
                acc[i][j] = MFMA16(a1[i], b1[j], acc[i][j]);
    }

#pragma unroll
    for (int i = 0; i < 2; ++i) {
#pragma unroll
        for (int j = 0; j < 4; ++j) {
            int col = n0 + wn * 64 + j * 16 + l;
            float bv = bias[col];
#pragma unroll
            for (int r = 0; r < 4; ++r) {
                int row = m0 + wm * 32 + i * 16 + q16 * 4 + r;
                outf[(size_t)row * N + col] = acc[i][j][r] + bv;
            }
        }
    }
}

// ---------------------------------------------------------------------------
// Flash attention (R14 version): 256 threads, double-buffered DMA staging,
// S^T on 32x32x16, static-max softmax, swap-free PV via pi-permuted V^T.
// XCD remap: 4 heads per XCD -> KV L2-resident.
// ---------------------------------------------------------------------------
__global__ __launch_bounds__(256, 2)
void attn_fused(const unsigned short* __restrict__ Q,
                const unsigned short* __restrict__ Km,
                const unsigned short* __restrict__ Vt,
                unsigned short* __restrict__ O)
{
    __shared__ unsigned short sK[2][128 * 64];
    __shared__ unsigned short sVt[2][64 * 128];

    const int tid  = threadIdx.x;
    const int wave = tid >> 6, lane = tid & 63;
    const int l31 = lane & 31, h = lane >> 5;
    const int swz = l31 & 7;
    const int bid = blockIdx.x;                  // 0..511
    const int slot = bid >> 3;                   // 0..63
    const int bh = (bid & 7) * 4 + (slot >> 4);  // 4 heads per XCD
    const int n0 = (slot & 15) * 128;
    const int q0 = n0 + wave * 32;

    const unsigned short* Kp = Km + (size_t)bh * 2048 * 64;
    const unsigned short* Vp = Vt + (size_t)bh * 64 * 2048;
    const unsigned short* sKf = &sK[0][0];
    const unsigned short* sVf = &sVt[0][0];

    int ka[4], va[2][2];
#pragma unroll
    for (int ks = 0; ks < 4; ++ks)
        ka[ks] = l31 * 64 + ((ks * 2 + h) ^ swz) * 8;
#pragma unroll
    for (int m1 = 0; m1 < 2; ++m1)
#pragma unroll
        for (int ks2 = 0; ks2 < 2; ++ks2)
            va[m1][ks2] = l31 * 128 + ((m1 * 4 + ks2 * 2 + h) ^ swz) * 8;

    int ksrc[4], vsrc[4], dst[4];
#pragma unroll
    for (int c = 0; c < 4; ++c) {
        int s = wave * 256 + c * 64 + lane;
        int rk = s >> 3;
        ksrc[c] = rk * 64 + ((s & 7) ^ (rk & 7)) * 8;
        int rv = s >> 4;
        vsrc[c] = rv * 2048 + ((s & 15) ^ (rv & 7)) * 8;
        dst[c] = s * 8;
    }

    bf16x8 qf[4];
#pragma unroll
    for (int ks = 0; ks < 4; ++ks)
        qf[ks] = *(const bf16x8*)(Q + (size_t)(bh * 2048 + q0 + l31) * 64 + ks * 16 + h * 8);

    f32x16 oacc[2];
#pragma unroll
    for (int dt = 0; dt < 2; ++dt)
#pragma unroll
        for (int e = 0; e < 16; ++e) oacc[dt][e] = 0.f;
    f32x16 Zv;
#pragma unroll
    for (int e = 0; e < 16; ++e) Zv[e] = 0.f;
    f32x2 l2 = {0.f, 0.f};

#pragma unroll
    for (int c = 0; c < 4; ++c) {
        async16(Kp + ksrc[c], (void*)(sKf + dst[c]));
        async16(Vp + vsrc[c], (void*)(sVf + dst[c]));
    }
    __syncthreads();

    for (int it = 0; it < 16; ++it) {
        const int nb = ((it + 1) & 1) * 8192;
        if (it < 15) {
            int kv = (it + 1) * 128;
#pragma unroll
            for (int c = 0; c < 4; ++c)
                async16(Kp + (size_t)kv * 64 + ksrc[c], (void*)(sKf + nb + dst[c]));
        }

        f32x16 sacc[4];
#pragma unroll
        for (int mt = 0; mt < 4; ++mt) {
            bf16x8 kf0 = *(const bf16x8*)(sKf + ka[0] + mt * 2048);
            sacc[mt] = MFMA32(kf0, qf[0], Zv);
#pragma unroll
            for (int ks = 1; ks < 4; ++ks) {
                bf16x8 kf = *(const bf16x8*)(sKf + ka[ks] + mt * 2048);
                sacc[mt] = MFMA32(kf, qf[ks], sacc[mt]);
            }
        }

        if (it < 15) {
            int kv = (it + 1) * 128;
#pragma unroll
            for (int c = 0; c < 4; ++c)
                async16(Vp + (size_t)kv + vsrc[c], (void*)(sVf + nb + dst[c]));
        }

        unsigned int pk[4][4][2];
#pragma unroll
        for (int mt = 0; mt < 4; ++mt)
#pragma unroll
            for (int g = 0; g < 4; ++g) {
                float p0 = fexp2(sacc[mt][4 * g + 0]);
                float p1 = fexp2(sacc[mt][4 * g + 1]);
                float p2 = fexp2(sacc[mt][4 * g + 2]);
                float p3 = fexp2(sacc[mt][4 * g + 3]);
                l2 += (f32x2){p0, p1};
                l2 += (f32x2){p2, p3};
                pk[mt][g][0] = __builtin_amdgcn_perm(
                    __builtin_bit_cast(unsigned int, p1),
                    __builtin_bit_cast(unsigned int, p0), 0x07060302u);
                pk[mt][g][1] = __builtin_amdgcn_perm(
                    __builtin_bit_cast(unsigned int, p3),
                    __builtin_bit_cast(unsigned int, p2), 0x07060302u);
            }

#pragma unroll
        for (int mt = 0; mt < 4; ++mt) {
#pragma unroll
            for (int ks2 = 0; ks2 < 2; ++ks2) {
                u32x4 bu;
                bu[0] = pk[mt][2 * ks2][0];
                bu[1] = pk[mt][2 * ks2][1];
                bu[2] = pk[mt][2 * ks2 + 1][0];
                bu[3] = pk[mt][2 * ks2 + 1][1];
                bf16x8 bfrag = __builtin_bit_cast(bf16x8, bu);
#pragma unroll
                for (int dt = 0; dt < 2; ++dt) {
                    bf16x8 vf = *(const bf16x8*)(sVf + va[mt & 1][ks2]
                                                 + (mt >> 1) * 64 + dt * 4096);
                    oacc[dt] = MFMA32(vf, bfrag, oacc[dt]);
                }
            }
        }

#pragma unroll
        for (int ks = 0; ks < 4; ++ks) ka[ks] ^= 8192;
        va[0][0] ^= 8192; va[0][1] ^= 8192; va[1][0] ^= 8192; va[1][1] ^= 8192;
        __syncthreads();
    }

    float l_run = l2[0] + l2[1];
    l_run += __shfl_xor(l_run, 32);
    const int b = bh >> 3, hh = bh & 7;
    float inv = 1.f / fmaxf(l_run, 1e-20f);
    unsigned short* obase = O + ((size_t)(b * 2048 + q0 + l31)) * 512 + hh * 64;
#pragma unroll
    for (int dt = 0; dt < 2; ++dt)
#pragma unroll
        for (int g = 0; g < 4; ++g) {
            int d = dt * 32 + 8 * g + 4 * h;
            unsigned int w0 = pk2(oacc[dt][4 * g + 0] * inv, oacc[dt][4 * g + 1] * inv);
            unsigned int w1 = pk2(oacc[dt][4 * g + 2] * inv, oacc[dt][4 * g + 3] * inv);
            uint2 w = {w0, w1};
            *(uint2*)(obase + d) = w;
        }
}

// ---------------------------------------------------------------------------
extern "C" void kernel_launch(void* const* d_in, const int* in_sizes, int n_in,
                              void* d_out, int out_size, void* d_ws, size_t ws_size,
                              hipStream_t stream)
{
    const float* x      = (const float*)d_in[0];  // [4,2048,512]
    const float* qkv_w  = (const float*)d_in[1];  // [1536,512]
    const float* qkv_b  = (const float*)d_in[2];  // [1536]
    const float* proj_w = (const float*)d_in[3];  // [512,512]
    const float* proj_b = (const float*)d_in[4];  // [512]

    const size_t PER = 4u * 8u * 2048u * 64u;     // 4,194,304 elems (8 MB bf16)
    unsigned short* q_ws  = (unsigned short*)d_ws;
    unsigned short* k_ws  = q_ws  + PER;
    unsigned short* vt_ws = k_ws  + PER;
    unsigned short* ao_ws = vt_ws + PER;          // 32 MB of ws total

    // bf16 scratch inside d_out (16 MB; dead until final GEMM overwrites it)
    unsigned short* xb = (unsigned short*)d_out;          // 8 MB
    unsigned short* wb = xb + PER;                        // 1.5 MB

    // 0) bulk fp32->bf16 of x and qkv_w
    cvt_bf16<<<dim3(640), 256, 0, stream>>>(x, qkv_w, xb, wb);
    // 1) QKV projection: M=8192, N=1536, K=512 (LDS-free, XCD-remapped)
    gemm_qkv<<<dim3(768), 256, 0, stream>>>(xb, wb, qkv_b, q_ws, k_ws, vt_ws, 512);
    // 2) Flash attention: 512 blocks, XCD-remapped (4 heads/XCD)
    attn_fused<<<dim3(512), 256, 0, stream>>>(q_ws, k_ws, vt_ws, ao_ws);
    // 3) proj_w fp32->bf16 into dead k_ws
    cvt_w2<<<dim3(128), 256, 0, stream>>>(proj_w, k_ws);
    // 4) Output projection: M=8192, N=512, K=512 (LDS-free, XCD-remapped)
    gemm_out<<<dim3(512), 256, 0, stream>>>(ao_ws, k_ws, proj_b, (float*)d_out, 512, 512);
}

// Round 17
// 154.357 us; speedup vs baseline: 1.2730x; 1.2730x over previous
//
#include <hip/hip_runtime.h>
#include <stdint.h>

// ---------------------------------------------------------------------------
// Fused MHA block: qkv proj -> flash attention -> out proj.
// Inputs fp32, output fp32; bf16 MFMA compute, fp32 accum.
// B=4 N=2048 C=512 H=8 D=64 fixed.
// R17: exact revert to R14 (best, 157.2us) + cvt_w2 folded into cvt_bf16
// (proj_w bf16 lives in ws region wb2; one fewer launch).
// ---------------------------------------------------------------------------

typedef short bf16x8 __attribute__((ext_vector_type(8)));   // 8 bf16 = 4 VGPRs
typedef float f32x2  __attribute__((ext_vector_type(2)));
typedef float f32x4  __attribute__((ext_vector_type(4)));
typedef float f32x16 __attribute__((ext_vector_type(16)));
typedef unsigned int u32x4 __attribute__((ext_vector_type(4)));

__device__ __forceinline__ unsigned short f2bf(float f) {
    unsigned int u = __builtin_bit_cast(unsigned int, f);
    u += 0x7fffu + ((u >> 16) & 1u);
    return (unsigned short)(u >> 16);
}
__device__ __forceinline__ unsigned int pk2(float a, float b) {
    return (unsigned int)f2bf(a) | ((unsigned int)f2bf(b) << 16);
}
__device__ __forceinline__ float fexp2(float x) {
    return __builtin_amdgcn_exp2f(x);    // bare v_exp_f32
}
__device__ __forceinline__ bf16x8 ld8_f32(const float* __restrict__ p) {
    float4 f0 = *(const float4*)p;
    float4 f1 = *(const float4*)(p + 4);
    u32x4 u = {pk2(f0.x, f0.y), pk2(f0.z, f0.w), pk2(f1.x, f1.y), pk2(f1.z, f1.w)};
    return __builtin_bit_cast(bf16x8, u);
}
__device__ __forceinline__ void async16(const void* g, void* l) {
    __builtin_amdgcn_global_load_lds(
        (const __attribute__((address_space(1))) unsigned int*)g,
        (__attribute__((address_space(3))) unsigned int*)l,
        16, 0, 0);
}

#define MFMA16(a, b, c) __builtin_amdgcn_mfma_f32_16x16x32_bf16((a), (b), (c), 0, 0, 0)
#define MFMA32(a, b, c) __builtin_amdgcn_mfma_f32_32x32x16_bf16((a), (b), (c), 0, 0, 0)

// ---------------------------------------------------------------------------
// fp32 -> bf16 bulk convert: x, qkv_w, proj_w in one pass.
// ---------------------------------------------------------------------------
__global__ void cvt_bf16(const float* __restrict__ x,
                         const float* __restrict__ w,
                         const float* __restrict__ w2,
                         unsigned short* __restrict__ xb,
                         unsigned short* __restrict__ wb,
                         unsigned short* __restrict__ wb2)
{
    const int G = 524288 + 98304 + 32768;
    for (int idx = blockIdx.x * 256 + threadIdx.x; idx < G; idx += gridDim.x * 256) {
        if (idx < 524288)
            *(bf16x8*)(xb + (size_t)idx * 8) = ld8_f32(x + (size_t)idx * 8);
        else if (idx < 524288 + 98304) {
            int j = idx - 524288;
            *(bf16x8*)(wb + (size_t)j * 8) = ld8_f32(w + (size_t)j * 8);
        } else {
            int j = idx - 524288 - 98304;
            *(bf16x8*)(wb2 + (size_t)j * 8) = ld8_f32(w2 + (size_t)j * 8);
        }
    }
}

// ---------------------------------------------------------------------------
// QKV GEMM: 128x128 tile / 4 waves; BK=32; dual DMA staging; 4 blocks/CU.
// XCD remap: XCD k owns A-rows [8k,8k+8) x all 12 col-tiles.
// ---------------------------------------------------------------------------
__global__ __launch_bounds__(256, 4)
void gemm_qkv(const unsigned short* __restrict__ A,
              const unsigned short* __restrict__ B,
              const float* __restrict__ bias,
              unsigned short* __restrict__ out0,
              unsigned short* __restrict__ out1,
              unsigned short* __restrict__ out2,
              int K)
{
    __shared__ unsigned short sA[128 * 32];
    __shared__ unsigned short sB[128 * 32];

    const int tid  = threadIdx.x;
    const int wave = tid >> 6, lane = tid & 63;
    const int l = lane & 15, q16 = lane >> 4;
    const int wm = wave >> 1, wn = wave & 1;
    const int bid = blockIdx.x;                  // 0..767
    const int slot = bid >> 3;                   // 0..95
    const int m0 = ((bid & 7) * 8 + slot / 12) * 128;
    const int n0 = (slot % 12) * 128;

    f32x4 acc[4][4];
#pragma unroll
    for (int i = 0; i < 4; ++i)
#pragma unroll
        for (int j = 0; j < 4; ++j)
            acc[i][j] = (f32x4){0.f, 0.f, 0.f, 0.f};

    for (int k0 = 0; k0 < K; k0 += 32) {
#pragma unroll
        for (int call = 0; call < 2; ++call) {
            int L = call * 256 + tid;
            int r = L >> 2, c = L & 3;
            async16(A + (size_t)(m0 + r) * K + k0 + c * 8, sA + L * 8);
            async16(B + (size_t)(n0 + r) * K + k0 + c * 8, sB + L * 8);
        }
        __syncthreads();

        bf16x8 af[4], bfr[4];
#pragma unroll
        for (int i = 0; i < 4; ++i)
            af[i] = *(const bf16x8*)(sA + ((wm * 64 + i * 16 + l) * 4 + q16) * 8);
#pragma unroll
        for (int j = 0; j < 4; ++j)
            bfr[j] = *(const bf16x8*)(sB + ((wn * 64 + j * 16 + l) * 4 + q16) * 8);
#pragma unroll
        for (int i = 0; i < 4; ++i)
#pragma unroll
            for (int j = 0; j < 4; ++j)
                acc[i][j] = MFMA16(af[i], bfr[j], acc[i][j]);
        __syncthreads();
    }

    const float lscale = 0.18033688f;  // D^-0.5 * log2(e), folded into q
#pragma unroll
    for (int i = 0; i < 4; ++i) {
#pragma unroll
        for (int j = 0; j < 4; ++j) {
            int col = n0 + wn * 64 + j * 16 + l;
            float bv = bias[col];
#pragma unroll
            for (int r = 0; r < 4; ++r) {
                int row = m0 + wm * 64 + i * 16 + q16 * 4 + r;
                float val = acc[i][j][r] + bv;
                int which = col >> 9;            // 0:q 1:k 2:v
                int h = (col >> 6) & 7, d = col & 63;
                int b = row >> 11, n = row & 2047;
                if (which == 0)
                    out0[(size_t)(((b * 8 + h) * 2048) + n) * 64 + d] = f2bf(val * lscale);
                else if (which == 1)
                    out1[(size_t)(((b * 8 + h) * 2048) + n) * 64 + d] = f2bf(val);
                else {
                    // V^T with pi(n): swap bits 2<->3 of n (within 32-blocks)
                    int np = (n & ~12) | ((n & 8) >> 1) | ((n & 4) << 1);
                    out2[(size_t)(((b * 8 + h) * 64) + d) * 2048 + np] = f2bf(val);
                }
            }
        }
    }
}

// ---------------------------------------------------------------------------
// Output GEMM: 64x128 tile / 4 waves; BK=32; 4 blocks/CU. fp32 out + bias.
// XCD remap: XCD k owns rows [16k,16k+16) x 4 col-tiles.
// ---------------------------------------------------------------------------
__global__ __launch_bounds__(256, 4)
void gemm_out(const unsigned short* __restrict__ A,
              const unsigned short* __restrict__ B,
              const float* __restrict__ bias,
              float* __restrict__ outf,
              int K, int N)
{
    __shared__ unsigned short sA[64 * 32];
    __shared__ unsigned short sB[128 * 32];

    const int tid  = threadIdx.x;
    const int wave = tid >> 6, lane = tid & 63;
    const int l = lane & 15, q16 = lane >> 4;
    const int wm = wave >> 1, wn = wave & 1;
    const int bid = blockIdx.x;                  // 0..511
    const int slot = bid >> 3;                   // 0..63
    const int m0 = ((bid & 7) * 16 + (slot >> 2)) * 64;
    const int n0 = (slot & 3) * 128;

    f32x4 acc[2][4];
#pragma unroll
    for (int i = 0; i < 2; ++i)
#pragma unroll
        for (int j = 0; j < 4; ++j)
            acc[i][j] = (f32x4){0.f, 0.f, 0.f, 0.f};

    for (int k0 = 0; k0 < K; k0 += 32) {
        {
            int r = tid >> 2, c = tid & 3;       // A: 256 slots
            async16(A + (size_t)(m0 + r) * K + k0 + c * 8, sA + tid * 8);
        }
#pragma unroll
        for (int call = 0; call < 2; ++call) {   // B: 512 slots
            int L = call * 256 + tid;
            int r = L >> 2, c = L & 3;
            async16(B + (size_t)(n0 + r) * K + k0 + c * 8, sB + L * 8);
        }
        __syncthreads();

        bf16x8 af[2], bfr[4];
#pragma unroll
        for (int i = 0; i < 2; ++i)
            af[i] = *(const bf16x8*)(sA + ((wm * 32 + i * 16 + l) * 4 + q16) * 8);
#pragma unroll
        for (int j = 0; j < 4; ++j)
            bfr[j] = *(const bf16x8*)(sB + ((wn * 64 + j * 16 + l) * 4 + q16) * 8);
#pragma unroll
        for (int i = 0; i < 2; ++i)
#pragma unroll
            for (int j = 0; j < 4; ++j)
                acc[i][j] = MFMA16(af[i], bfr[j], acc[i][j]);
        __syncthreads();
    }

#pragma unroll
    for (int i = 0; i < 2; ++i) {
#pragma unroll
        for (int j = 0; j < 4; ++j) {
            int col = n0 + wn * 64 + j * 16 + l;
            float bv = bias[col];
#pragma unroll
            for (int r = 0; r < 4; ++r) {
                int row = m0 + wm * 32 + i * 16 + q16 * 4 + r;
                outf[(size_t)row * N + col] = acc[i][j][r] + bv;
            }
        }
    }
}

// ---------------------------------------------------------------------------
// Flash attention (R14 version): 256 threads, double-buffered DMA staging,
// S^T on 32x32x16, static-max softmax, swap-free PV via pi-permuted V^T.
// XCD remap: 4 heads per XCD -> KV L2-resident.
// ---------------------------------------------------------------------------
__global__ __launch_bounds__(256, 2)
void attn_fused(const unsigned short* __restrict__ Q,
                const unsigned short* __restrict__ Km,
                const unsigned short* __restrict__ Vt,
                unsigned short* __restrict__ O)
{
    __shared__ unsigned short sK[2][128 * 64];
    __shared__ unsigned short sVt[2][64 * 128];

    const int tid  = threadIdx.x;
    const int wave = tid >> 6, lane = tid & 63;
    const int l31 = lane & 31, h = lane >> 5;
    const int swz = l31 & 7;
    const int bid = blockIdx.x;                  // 0..511
    const int slot = bid >> 3;                   // 0..63
    const int bh = (bid & 7) * 4 + (slot >> 4);  // 4 heads per XCD
    const int n0 = (slot & 15) * 128;
    const int q0 = n0 + wave * 32;

    const unsigned short* Kp = Km + (size_t)bh * 2048 * 64;
    const unsigned short* Vp = Vt + (size_t)bh * 64 * 2048;
    const unsigned short* sKf = &sK[0][0];
    const unsigned short* sVf = &sVt[0][0];

    int ka[4], va[2][2];
#pragma unroll
    for (int ks = 0; ks < 4; ++ks)
        ka[ks] = l31 * 64 + ((ks * 2 + h) ^ swz) * 8;
#pragma unroll
    for (int m1 = 0; m1 < 2; ++m1)
#pragma unroll
        for (int ks2 = 0; ks2 < 2; ++ks2)
            va[m1][ks2] = l31 * 128 + ((m1 * 4 + ks2 * 2 + h) ^ swz) * 8;

    int ksrc[4], vsrc[4], dst[4];
#pragma unroll
    for (int c = 0; c < 4; ++c) {
        int s = wave * 256 + c * 64 + lane;
        int rk = s >> 3;
        ksrc[c] = rk * 64 + ((s & 7) ^ (rk & 7)) * 8;
        int rv = s >> 4;
        vsrc[c] = rv * 2048 + ((s & 15) ^ (rv & 7)) * 8;
        dst[c] = s * 8;
    }

    bf16x8 qf[4];
#pragma unroll
    for (int ks = 0; ks < 4; ++ks)
        qf[ks] = *(const bf16x8*)(Q + (size_t)(bh * 2048 + q0 + l31) * 64 + ks * 16 + h * 8);

    f32x16 oacc[2];
#pragma unroll
    for (int dt = 0; dt < 2; ++dt)
#pragma unroll
        for (int e = 0; e < 16; ++e) oacc[dt][e] = 0.f;
    f32x16 Zv;
#pragma unroll
    for (int e = 0; e < 16; ++e) Zv[e] = 0.f;
    f32x2 l2 = {0.f, 0.f};

#pragma unroll
    for (int c = 0; c < 4; ++c) {
        async16(Kp + ksrc[c], (void*)(sKf + dst[c]));
        async16(Vp + vsrc[c], (void*)(sVf + dst[c]));
    }
    __syncthreads();

    for (int it = 0; it < 16; ++it) {
        const int nb = ((it + 1) & 1) * 8192;
        if (it < 15) {
            int kv = (it + 1) * 128;
#pragma unroll
            for (int c = 0; c < 4; ++c)
                async16(Kp + (size_t)kv * 64 + ksrc[c], (void*)(sKf + nb + dst[c]));
        }

        f32x16 sacc[4];
#pragma unroll
        for (int mt = 0; mt < 4; ++mt) {
            bf16x8 kf0 = *(const bf16x8*)(sKf + ka[0] + mt * 2048);
            sacc[mt] = MFMA32(kf0, qf[0], Zv);
#pragma unroll
            for (int ks = 1; ks < 4; ++ks) {
                bf16x8 kf = *(const bf16x8*)(sKf + ka[ks] + mt * 2048);
                sacc[mt] = MFMA32(kf, qf[ks], sacc[mt]);
            }
        }

        if (it < 15) {
            int kv = (it + 1) * 128;
#pragma unroll
            for (int c = 0; c < 4; ++c)
                async16(Vp + (size_t)kv + vsrc[c], (void*)(sVf + nb + dst[c]));
        }

        unsigned int pk[4][4][2];
#pragma unroll
        for (int mt = 0; mt < 4; ++mt)
#pragma unroll
            for (int g = 0; g < 4; ++g) {
                float p0 = fexp2(sacc[mt][4 * g + 0]);
                float p1 = fexp2(sacc[mt][4 * g + 1]);
                float p2 = fexp2(sacc[mt][4 * g + 2]);
                float p3 = fexp2(sacc[mt][4 * g + 3]);
                l2 += (f32x2){p0, p1};
                l2 += (f32x2){p2, p3};
                pk[mt][g][0] = __builtin_amdgcn_perm(
                    __builtin_bit_cast(unsigned int, p1),
                    __builtin_bit_cast(unsigned int, p0), 0x07060302u);
                pk[mt][g][1] = __builtin_amdgcn_perm(
                    __builtin_bit_cast(unsigned int, p3),
                    __builtin_bit_cast(unsigned int, p2), 0x07060302u);
            }

#pragma unroll
        for (int mt = 0; mt < 4; ++mt) {
#pragma unroll
            for (int ks2 = 0; ks2 < 2; ++ks2) {
                u32x4 bu;
                bu[0] = pk[mt][2 * ks2][0];
                bu[1] = pk[mt][2 * ks2][1];
                bu[2] = pk[mt][2 * ks2 + 1][0];
                bu[3] = pk[mt][2 * ks2 + 1][1];
                bf16x8 bfrag = __builtin_bit_cast(bf16x8, bu);
#pragma unroll
                for (int dt = 0; dt < 2; ++dt) {
                    bf16x8 vf = *(const bf16x8*)(sVf + va[mt & 1][ks2]
                                                 + (mt >> 1) * 64 + dt * 4096);
                    oacc[dt] = MFMA32(vf, bfrag, oacc[dt]);
                }
            }
        }

#pragma unroll
        for (int ks = 0; ks < 4; ++ks) ka[ks] ^= 8192;
        va[0][0] ^= 8192; va[0][1] ^= 8192; va[1][0] ^= 8192; va[1][1] ^= 8192;
        __syncthreads();
    }

    float l_run = l2[0] + l2[1];
    l_run += __shfl_xor(l_run, 32);
    const int b = bh >> 3, hh = bh & 7;
    float inv = 1.f / fmaxf(l_run, 1e-20f);
    unsigned short* obase = O + ((size_t)(b * 2048 + q0 + l31)) * 512 + hh * 64;
#pragma unroll
    for (int dt = 0; dt < 2; ++dt)
#pragma unroll
        for (int g = 0; g < 4; ++g) {
            int d = dt * 32 + 8 * g + 4 * h;
            unsigned int w0 = pk2(oacc[dt][4 * g + 0] * inv, oacc[dt][4 * g + 1] * inv);
            unsigned int w1 = pk2(oacc[dt][4 * g + 2] * inv, oacc[dt][4 * g + 3] * inv);
            uint2 w = {w0, w1};
            *(uint2*)(obase + d) = w;
        }
}

// ---------------------------------------------------------------------------
extern "C" void kernel_launch(void* const* d_in, const int* in_sizes, int n_in,
                              void* d_out, int out_size, void* d_ws, size_t ws_size,
                              hipStream_t stream)
{
    const float* x      = (const float*)d_in[0];  // [4,2048,512]
    const float* qkv_w  = (const float*)d_in[1];  // [1536,512]
    const float* qkv_b  = (const float*)d_in[2];  // [1536]
    const float* proj_w = (const float*)d_in[3];  // [512,512]
    const float* proj_b = (const float*)d_in[4];  // [512]

    const size_t PER = 4u * 8u * 2048u * 64u;     // 4,194,304 elems (8 MB bf16)
    unsigned short* q_ws  = (unsigned short*)d_ws;
    unsigned short* k_ws  = q_ws  + PER;
    unsigned short* vt_ws = k_ws  + PER;
    unsigned short* ao_ws = vt_ws + PER;
    unsigned short* wb2   = ao_ws + PER;          // proj_w bf16 (0.5 MB)

    // bf16 scratch inside d_out (16 MB; dead until final GEMM overwrites it)
    unsigned short* xb = (unsigned short*)d_out;          // 8 MB
    unsigned short* wb = xb + PER;                        // 1.5 MB

    // 0) bulk fp32->bf16 of x, qkv_w, proj_w (one launch)
    cvt_bf16<<<dim3(640), 256, 0, stream>>>(x, qkv_w, proj_w, xb, wb, wb2);
    // 1) QKV projection: M=8192, N=1536, K=512 (XCD-remapped)
    gemm_qkv<<<dim3(768), 256, 0, stream>>>(xb, wb, qkv_b, q_ws, k_ws, vt_ws, 512);
    // 2) Flash attention: 512 blocks, XCD-remapped (4 heads/XCD)
    attn_fused<<<dim3(512), 256, 0, stream>>>(q_ws, k_ws, vt_ws, ao_ws);
    // 3) Output projection: M=8192, N=512, K=512 (XCD-remapped)
    gemm_out<<<dim3(512), 256, 0, stream>>>(ao_ws, wb2, proj_b, (float*)d_out, 512, 512);
}